// Round 2
// baseline (823.076 us; speedup 1.0000x reference)
//
#include <hip/hip_runtime.h>

#define HID 512
#define SLEN 4096
#define NB 8
#define BSROWS (NB*SLEN)     // 32768 rows per direction
#define NLAYER 4
#define CHUNKT 128
#define NCHUNK 32

typedef float f32x4 __attribute__((ext_vector_type(4)));
typedef unsigned int u32x4 __attribute__((ext_vector_type(4)));

__device__ __forceinline__ float bf2f(unsigned short u){
  union { unsigned int i; float f; } v; v.i = ((unsigned int)u) << 16; return v.f;
}
__device__ __forceinline__ unsigned short f2bf(float f){
  union { float f; unsigned int i; } v; v.f = f;
  unsigned int u = v.i;
  u = u + 0x7fffu + ((u >> 16) & 1u);
  return (unsigned short)(u >> 16);
}
__device__ __forceinline__ void mfma_bf16(f32x4& acc, u32x4 a, u32x4 b){
  asm("v_mfma_f32_16x16x32_bf16 %0, %1, %2, %0" : "+v"(acc) : "v"(a), "v"(b));
}
// MFMA D-write -> VALU read hazard fence (inline asm is opaque to the
// hazard recognizer; CDNA has no HW interlock here). sched_barrier pins
// the nops between the MFMA cluster and the epilogue reads.
__device__ __forceinline__ void mfma_fence(){
  __builtin_amdgcn_sched_barrier(0);
  asm volatile("s_nop 7\n\ts_nop 7\n\ts_nop 7\n\ts_nop 7");
  __builtin_amdgcn_sched_barrier(0);
}

// ---------------- prep kernels ----------------

__global__ __launch_bounds__(256) void prep_w(
    const float* __restrict__ wzf, const float* __restrict__ whf,
    const float* __restrict__ wzb, const float* __restrict__ whb,
    unsigned short* __restrict__ wbf)
{
  int idx = blockIdx.x*256 + threadIdx.x;   // 524288 total
  int i8  = idx & 63;
  int o   = (idx >> 6) & 511;
  int m   = (idx >> 15) & 1;
  int l   = (idx >> 16) & 3;
  int dir = idx >> 18;
  const float* src = dir ? (m ? whb : wzb) : (m ? whf : wzf);
  const float* p = src + ((size_t)(l*512 + o)*512 + i8*8);
  float4 v0 = *(const float4*)p;
  float4 v1 = *(const float4*)(p+4);
  unsigned short* q = wbf + ((((size_t)(dir*4 + l)*2 + m)*512 + o)*512 + i8*8);
  u32x4 outv;
  outv[0] = (unsigned)f2bf(v0.x) | ((unsigned)f2bf(v0.y)<<16);
  outv[1] = (unsigned)f2bf(v0.z) | ((unsigned)f2bf(v0.w)<<16);
  outv[2] = (unsigned)f2bf(v1.x) | ((unsigned)f2bf(v1.y)<<16);
  outv[3] = (unsigned)f2bf(v1.z) | ((unsigned)f2bf(v1.w)<<16);
  *(u32x4*)q = outv;
}

__global__ __launch_bounds__(256) void prep_fw(
    const float* __restrict__ fw, unsigned short* __restrict__ outw)
{
  int idx = blockIdx.x*256 + threadIdx.x;   // 65536
  const float* p = fw + (size_t)idx*8;
  float4 v0 = *(const float4*)p;
  float4 v1 = *(const float4*)(p+4);
  u32x4 outv;
  outv[0] = (unsigned)f2bf(v0.x) | ((unsigned)f2bf(v0.y)<<16);
  outv[1] = (unsigned)f2bf(v0.z) | ((unsigned)f2bf(v0.w)<<16);
  outv[2] = (unsigned)f2bf(v1.x) | ((unsigned)f2bf(v1.y)<<16);
  outv[3] = (unsigned)f2bf(v1.z) | ((unsigned)f2bf(v1.w)<<16);
  *(u32x4*)(outw + (size_t)idx*8) = outv;
}

__global__ __launch_bounds__(256) void prep_x(
    const float* __restrict__ x, unsigned short* __restrict__ X0)
{
  int idx = blockIdx.x*256 + threadIdx.x;   // 4194304
  int j8  = idx & 63;
  int s   = (idx >> 6) & 4095;
  int b   = (idx >> 18) & 7;
  int dir = idx >> 21;
  int srcs = dir ? (4095 - s) : s;
  const float* p = x + ((size_t)(b*SLEN + srcs)*512 + j8*8);
  float4 v0 = *(const float4*)p;
  float4 v1 = *(const float4*)(p+4);
  u32x4 outv;
  outv[0] = (unsigned)f2bf(v0.x) | ((unsigned)f2bf(v0.y)<<16);
  outv[1] = (unsigned)f2bf(v0.z) | ((unsigned)f2bf(v0.w)<<16);
  outv[2] = (unsigned)f2bf(v1.x) | ((unsigned)f2bf(v1.y)<<16);
  outv[3] = (unsigned)f2bf(v1.z) | ((unsigned)f2bf(v1.w)<<16);
  *(u32x4*)(X0 + ((size_t)((dir*NB + b)*SLEN + s)*512 + j8*8)) = outv;
}

// ---------------- gate GEMM (z & h_tilde fused, gate epilogue) ----------------
// Block: 256 thr (4 waves). Tile: 128 rows x 64 h-cols, Wz and Wh both.
// Writes a,b as 16-bit fixed point packed in u32 (group-local buffer).

__global__ __launch_bounds__(256) void gate_gemm(
    const unsigned short* __restrict__ X,    // group base [R][512] bf16
    const unsigned short* __restrict__ Wz,   // [512][512] bf16
    const unsigned short* __restrict__ Wh,
    const float* __restrict__ bzp, const float* __restrict__ bhp,  // [512]
    unsigned int* __restrict__ ab,           // [R][512] packed
    int Mtiles)
{
  __shared__ __align__(16) unsigned short As[128*64];
  __shared__ __align__(16) unsigned short Bzs[64*64];
  __shared__ __align__(16) unsigned short Bhs[64*64];

  int hw = blockIdx.x;
  int lg = (hw & 7)*Mtiles + (hw >> 3);     // XCD-chunked swizzle (grid = 8*Mtiles)
  int nt  = lg & 7;
  int mt  = lg >> 3;

  const int tid = threadIdx.x;
  const int lane = tid & 63;
  const int wv = tid >> 6;
  const int n0 = nt*64;
  const int slot = tid & 7;
  const int rowb = tid >> 3;

  f32x4 accz[2][4], acch[2][4];
  #pragma unroll
  for (int i=0;i<2;++i)
    #pragma unroll
    for (int j=0;j<4;++j){ accz[i][j] = (f32x4)(0.f); acch[i][j] = (f32x4)(0.f); }

  for (int ks=0; ks<8; ++ks){
    int k0 = ks*64;
    #pragma unroll
    for (int it=0; it<4; ++it){
      int row = rowb + it*32;
      u32x4 v = *(const u32x4*)(X + (size_t)(mt*128+row)*512 + k0 + slot*8);
      *(u32x4*)(As + row*64 + ((slot ^ (row&7))<<3)) = v;
    }
    #pragma unroll
    for (int it=0; it<2; ++it){
      int row = rowb + it*32;
      u32x4 vz = *(const u32x4*)(Wz + (size_t)(n0+row)*512 + k0 + slot*8);
      *(u32x4*)(Bzs + row*64 + ((slot ^ (row&7))<<3)) = vz;
      u32x4 vh = *(const u32x4*)(Wh + (size_t)(n0+row)*512 + k0 + slot*8);
      *(u32x4*)(Bhs + row*64 + ((slot ^ (row&7))<<3)) = vh;
    }
    __syncthreads();
    #pragma unroll
    for (int kk=0; kk<2; ++kk){
      int kslot = kk*4 + (lane >> 4);
      u32x4 af[2];
      #pragma unroll
      for (int mf=0; mf<2; ++mf){
        int row = wv*32 + mf*16 + (lane & 15);
        af[mf] = *(const u32x4*)(As + row*64 + ((kslot ^ (row&7))<<3));
      }
      #pragma unroll
      for (int nf=0; nf<4; ++nf){
        int row = nf*16 + (lane & 15);
        u32x4 bz = *(const u32x4*)(Bzs + row*64 + ((kslot ^ (row&7))<<3));
        u32x4 bh = *(const u32x4*)(Bhs + row*64 + ((kslot ^ (row&7))<<3));
        #pragma unroll
        for (int mf=0; mf<2; ++mf){
          mfma_bf16(accz[mf][nf], af[mf], bz);
          mfma_bf16(acch[mf][nf], af[mf], bh);
        }
      }
    }
    __syncthreads();
  }
  mfma_fence();

  #pragma unroll
  for (int nf=0; nf<4; ++nf){
    int col = n0 + nf*16 + (lane & 15);
    float bz = bzp[col];
    float bh = bhp[col];
    #pragma unroll
    for (int mf=0; mf<2; ++mf){
      int rb = mt*128 + wv*32 + mf*16 + ((lane>>4)<<2);
      #pragma unroll
      for (int r=0; r<4; ++r){
        float zp = accz[mf][nf][r] + bz;
        float hp = acch[mf][nf][r] + bh;
        float sg = 1.f/(1.f + __expf(-zp));
        float th = 1.f - 2.f/(1.f + __expf(2.f*hp));
        float a = 1.f - sg;
        a = fminf(fmaxf(a, 1e-8f), 1.0f);   // ref clip hi = 1-1e-8, rounds to 1.0f
        float bv = sg*th;                    // |bv| < 1
        unsigned aq = (unsigned)fmaf(a, 65535.f, 0.5f);
        unsigned bq = (unsigned)fmaf(bv, 32767.5f, 32768.0f);
        ab[(size_t)(rb + r)*512 + col] = aq | (bq << 16);
      }
    }
  }
}

// ---------------- chunked scan (f32 arithmetic, fixed-point decode) ----------------

__device__ __forceinline__ void decode_ab(unsigned int v, float& a, float& b){
  a = (float)(v & 0xffffu) * (1.f/65535.f);
  b = fmaf((float)(v >> 16), 2.f/65535.f, -1.f);
}

__global__ __launch_bounds__(256) void scan_p1(
    const unsigned int* __restrict__ ab,
    float* __restrict__ Aagg, float* __restrict__ Bagg, int CG)
{
  int idx = blockIdx.x*256 + threadIdx.x;   // CG*32
  int h  = idx & 511;
  int rest = idx >> 9;
  int c  = rest & 31;
  int bl = rest >> 5;
  const unsigned int* p = ab + ((size_t)(bl*SLEN + c*CHUNKT))*512 + h;
  float A = 1.f, Bv = 0.f;
  #pragma unroll 8
  for (int t=0; t<CHUNKT; ++t){
    float a, b; decode_ab(p[(size_t)t*512], a, b);
    Bv = fmaf(a, Bv, b);
    A *= a;
  }
  int chain = bl*512 + h;
  Aagg[c*CG + chain] = A;
  Bagg[c*CG + chain] = Bv;
}

__global__ __launch_bounds__(256) void scan_p2(
    const float* __restrict__ Aagg, const float* __restrict__ Bagg,
    float* __restrict__ Hin, int CG)
{
  int chain = blockIdx.x*256 + threadIdx.x;  // CG threads
  float hv = 0.f;
  #pragma unroll
  for (int c=0; c<NCHUNK; ++c){
    Hin[c*CG + chain] = hv;
    hv = fmaf(Aagg[c*CG + chain], hv, Bagg[c*CG + chain]);
  }
}

__global__ __launch_bounds__(256) void scan_p3(
    const unsigned int* __restrict__ ab,
    const float* __restrict__ Hin,
    unsigned short* __restrict__ hb, int CG)
{
  int idx = blockIdx.x*256 + threadIdx.x;
  int h  = idx & 511;
  int rest = idx >> 9;
  int c  = rest & 31;
  int bl = rest >> 5;
  int chain = bl*512 + h;
  float hv = Hin[c*CG + chain];
  const unsigned int* p = ab + ((size_t)(bl*SLEN + c*CHUNKT))*512 + h;
  unsigned short* q = hb + ((size_t)(bl*SLEN + c*CHUNKT))*512 + h;
  #pragma unroll 8
  for (int t=0; t<CHUNKT; ++t){
    float a, b; decode_ab(p[(size_t)t*512], a, b);
    hv = fmaf(a, hv, b);
    q[(size_t)t*512] = f2bf(hv);
  }
}

// ---------------- residual + LayerNorm (in-place on X) ----------------

__global__ __launch_bounds__(256) void ln_kernel(
    const unsigned short* __restrict__ hb,   // group [R][512] bf16
    unsigned short* __restrict__ Xio,        // group [R][512] bf16, in/out
    const float* __restrict__ g, const float* __restrict__ bta, int resid)
{
  int token = blockIdx.x*4 + (threadIdx.x >> 6);
  int lane = threadIdx.x & 63;
  size_t base = (size_t)token*512 + lane*8;
  u32x4 hv = *(const u32x4*)(hb + base);
  float v[8];
  #pragma unroll
  for (int w=0; w<4; ++w){
    v[2*w]   = bf2f((unsigned short)(hv[w] & 0xffffu));
    v[2*w+1] = bf2f((unsigned short)(hv[w] >> 16));
  }
  if (resid){
    u32x4 xv = *(const u32x4*)(Xio + base);
    #pragma unroll
    for (int w=0; w<4; ++w){
      v[2*w]   += bf2f((unsigned short)(xv[w] & 0xffffu));
      v[2*w+1] += bf2f((unsigned short)(xv[w] >> 16));
    }
  }
  float s = 0.f, s2 = 0.f;
  #pragma unroll
  for (int j=0; j<8; ++j){ s += v[j]; s2 += v[j]*v[j]; }
  #pragma unroll
  for (int o=1; o<64; o<<=1){ s += __shfl_xor(s, o, 64); s2 += __shfl_xor(s2, o, 64); }
  float mu = s * (1.f/512.f);
  float var = s2 * (1.f/512.f) - mu*mu;
  float inv = rsqrtf(var + 1e-5f);
  float4 g0 = *(const float4*)(g + lane*8);
  float4 g1 = *(const float4*)(g + lane*8 + 4);
  float4 b0 = *(const float4*)(bta + lane*8);
  float4 b1 = *(const float4*)(bta + lane*8 + 4);
  float gg[8]  = {g0.x,g0.y,g0.z,g0.w,g1.x,g1.y,g1.z,g1.w};
  float bbv[8] = {b0.x,b0.y,b0.z,b0.w,b1.x,b1.y,b1.z,b1.w};
  u32x4 outv;
  #pragma unroll
  for (int w=0; w<4; ++w){
    float y0 = (v[2*w]   - mu)*inv*gg[2*w]   + bbv[2*w];
    float y1 = (v[2*w+1] - mu)*inv*gg[2*w+1] + bbv[2*w+1];
    outv[w] = (unsigned)f2bf(y0) | ((unsigned)f2bf(y1) << 16);
  }
  *(u32x4*)(Xio + base) = outv;
}

// ---------------- fusion GEMM: out = [fwd, flip(bwd)] @ Wf^T + fb ----------------

__global__ __launch_bounds__(256) void fusion_gemm(
    const unsigned short* __restrict__ Xf,   // [2*BSROWS][512] final LN outputs
    const unsigned short* __restrict__ Wf,   // [512][1024] bf16
    const float* __restrict__ fb,
    float* __restrict__ outp)
{
  __shared__ __align__(16) unsigned short As[128*64];
  __shared__ __align__(16) unsigned short Bs[64*64];

  int hw = blockIdx.x;
  int lg = (hw & 7)*256 + (hw >> 3);   // 2048 blocks
  int nt = lg & 7;
  int mt = lg >> 3;                    // 0..255

  const int tid = threadIdx.x;
  const int lane = tid & 63;
  const int wv = tid >> 6;
  const int n0 = nt*64;
  const int slot = tid & 7;
  const int rowb = tid >> 3;

  f32x4 acc[2][4];
  #pragma unroll
  for (int i=0;i<2;++i)
    #pragma unroll
    for (int j=0;j<4;++j) acc[i][j] = (f32x4)(0.f);

  for (int ks=0; ks<16; ++ks){
    int k0 = ks*64;
    const unsigned short* Abase = Xf + ((k0 >= 512) ? (size_t)BSROWS*512 : 0);
    int kc = k0 & 511;
    #pragma unroll
    for (int it=0; it<4; ++it){
      int row = rowb + it*32;
      int rg = mt*128 + row;
      int sr = (k0 >= 512) ? (rg ^ 4095) : rg;   // flip s within batch for bwd half
      u32x4 v = *(const u32x4*)(Abase + (size_t)sr*512 + kc + slot*8);
      *(u32x4*)(As + row*64 + ((slot ^ (row&7))<<3)) = v;
    }
    #pragma unroll
    for (int it=0; it<2; ++it){
      int row = rowb + it*32;
      u32x4 v = *(const u32x4*)(Wf + (size_t)(n0+row)*1024 + k0 + slot*8);
      *(u32x4*)(Bs + row*64 + ((slot ^ (row&7))<<3)) = v;
    }
    __syncthreads();
    #pragma unroll
    for (int kk=0; kk<2; ++kk){
      int kslot = kk*4 + (lane >> 4);
      u32x4 af[2];
      #pragma unroll
      for (int mf=0; mf<2; ++mf){
        int row = wv*32 + mf*16 + (lane & 15);
        af[mf] = *(const u32x4*)(As + row*64 + ((kslot ^ (row&7))<<3));
      }
      #pragma unroll
      for (int nf=0; nf<4; ++nf){
        int row = nf*16 + (lane & 15);
        u32x4 bv = *(const u32x4*)(Bs + row*64 + ((kslot ^ (row&7))<<3));
        #pragma unroll
        for (int mf=0; mf<2; ++mf) mfma_bf16(acc[mf][nf], af[mf], bv);
      }
    }
    __syncthreads();
  }
  mfma_fence();

  #pragma unroll
  for (int nf=0; nf<4; ++nf){
    int col = n0 + nf*16 + (lane & 15);
    float bias = fb[col];
    #pragma unroll
    for (int mf=0; mf<2; ++mf){
      int rb = mt*128 + wv*32 + mf*16 + ((lane>>4)<<2);
      #pragma unroll
      for (int r=0; r<4; ++r)
        outp[(size_t)(rb + r)*512 + col] = acc[mf][nf][r] + bias;
    }
  }
}

// ---------------- launch ----------------

extern "C" void kernel_launch(void* const* d_in, const int* in_sizes, int n_in,
                              void* d_out, int out_size, void* d_ws, size_t ws_size,
                              hipStream_t stream)
{
  (void)in_sizes; (void)n_in; (void)out_size;
  const float* x   = (const float*)d_in[0];
  const float* wzf = (const float*)d_in[1];
  const float* bzf = (const float*)d_in[2];
  const float* whf = (const float*)d_in[3];
  const float* bhf = (const float*)d_in[4];
  const float* wzb = (const float*)d_in[5];
  const float* bzb = (const float*)d_in[6];
  const float* whb = (const float*)d_in[7];
  const float* bhb = (const float*)d_in[8];
  const float* fw  = (const float*)d_in[9];
  const float* fbb = (const float*)d_in[10];
  const float* lng = (const float*)d_in[11];
  const float* lnb = (const float*)d_in[12];
  float* outp = (float*)d_out;

  // Pick the largest per-direction batch-group count SG that fits ws_size.
  const size_t WbfB = (size_t)16*512*512*2;        // 8 MiB
  const size_t WfbB = (size_t)512*1024*2;          // 1 MiB
  const size_t XB   = (size_t)2*BSROWS*512*2;      // 64 MiB
  const size_t aggB = (size_t)4096*NCHUNK*4;       // 512 KiB (max CG)
  int SG = 8;
  for (int c = 1; c <= 8; c <<= 1){
    size_t need = WbfB + WfbB + XB + 3*aggB
                + ((size_t)BSROWS/c)*512*4          // AB
                + ((size_t)BSROWS/c)*512*2          // Hh
                + 1024;
    if (need <= ws_size){ SG = c; break; }
  }
  const int R  = BSROWS / SG;      // rows per group
  const int NBg = NB / SG;         // batches per group
  const int CG = NBg * 512;        // scan chains per group
  const int Mtiles = R / 128;

  char* ws = (char*)d_ws;
  size_t o = 0;
  unsigned short* Wbf = (unsigned short*)(ws + o); o += WbfB;
  unsigned short* Wfb = (unsigned short*)(ws + o); o += WfbB;
  unsigned short* X   = (unsigned short*)(ws + o); o += XB;
  unsigned int*   AB  = (unsigned int*)  (ws + o); o += (size_t)R*512*4;
  unsigned short* Hh  = (unsigned short*)(ws + o); o += (size_t)R*512*2;
  float* Aagg = (float*)(ws + o); o += aggB;
  float* Bagg = (float*)(ws + o); o += aggB;
  float* Hin  = (float*)(ws + o); o += aggB;

  prep_w <<<2048, 256, 0, stream>>>(wzf, whf, wzb, whb, Wbf);
  prep_fw<<<256,  256, 0, stream>>>(fw, Wfb);
  prep_x <<<16384,256, 0, stream>>>(x, X);

  for (int dir = 0; dir < 2; ++dir){
    const float* bz = dir ? bzb : bzf;
    const float* bh = dir ? bhb : bhf;
    for (int g = 0; g < SG; ++g){
      unsigned short* Xg = X + ((size_t)dir*BSROWS + (size_t)g*R)*512;
      for (int l = 0; l < NLAYER; ++l){
        const unsigned short* Wz = Wbf + ((size_t)((dir*4 + l)*2 + 0))*(512*512);
        const unsigned short* Wh = Wbf + ((size_t)((dir*4 + l)*2 + 1))*(512*512);
        gate_gemm<<<Mtiles*8, 256, 0, stream>>>(Xg, Wz, Wh, bz + l*512, bh + l*512, AB, Mtiles);
        scan_p1  <<<CG*NCHUNK/256, 256, 0, stream>>>(AB, Aagg, Bagg, CG);
        scan_p2  <<<CG/256,        256, 0, stream>>>(Aagg, Bagg, Hin, CG);
        scan_p3  <<<CG*NCHUNK/256, 256, 0, stream>>>(AB, Hin, Hh, CG);
        ln_kernel<<<R/4,           256, 0, stream>>>(Hh, Xg, lng, lnb, l > 0 ? 1 : 0);
      }
    }
  }
  fusion_gemm<<<2048, 256, 0, stream>>>(X, Wfb, fbb, outp);
}

// Round 3
// 710.166 us; speedup vs baseline: 1.1590x; 1.1590x over previous
//
#include <hip/hip_runtime.h>

#define HID 512
#define SLEN 4096
#define NB 8
#define BSROWS (NB*SLEN)     // 32768 rows per direction
#define NLAYER 4
#define CHUNKT 128
#define NCHUNK 32

typedef float f32x4 __attribute__((ext_vector_type(4)));
typedef unsigned int u32x4 __attribute__((ext_vector_type(4)));

__device__ __forceinline__ float bf2f(unsigned short u){
  union { unsigned int i; float f; } v; v.i = ((unsigned int)u) << 16; return v.f;
}
__device__ __forceinline__ unsigned short f2bf(float f){
  union { float f; unsigned int i; } v; v.f = f;
  unsigned int u = v.i;
  u = u + 0x7fffu + ((u >> 16) & 1u);
  return (unsigned short)(u >> 16);
}
__device__ __forceinline__ void mfma_bf16(f32x4& acc, u32x4 a, u32x4 b){
  asm("v_mfma_f32_16x16x32_bf16 %0, %1, %2, %0" : "+v"(acc) : "v"(a), "v"(b));
}
// MFMA D-write -> VALU read hazard fence (inline asm is opaque to the
// hazard recognizer; CDNA has no HW interlock here).
__device__ __forceinline__ void mfma_fence(){
  __builtin_amdgcn_sched_barrier(0);
  asm volatile("s_nop 7\n\ts_nop 7\n\ts_nop 7\n\ts_nop 7");
  __builtin_amdgcn_sched_barrier(0);
}
__device__ __forceinline__ void decode_ab(unsigned int v, float& a, float& b){
  a = (float)(v & 0xffffu) * (1.f/65535.f);
  b = fmaf((float)(v >> 16), 2.f/65535.f, -1.f);
}

// ---------------- prep kernels ----------------

__global__ __launch_bounds__(256) void prep_w(
    const float* __restrict__ wzf, const float* __restrict__ whf,
    const float* __restrict__ wzb, const float* __restrict__ whb,
    unsigned short* __restrict__ wbf)
{
  int idx = blockIdx.x*256 + threadIdx.x;   // 524288 total
  int i8  = idx & 63;
  int o   = (idx >> 6) & 511;
  int m   = (idx >> 15) & 1;
  int l   = (idx >> 16) & 3;
  int dir = idx >> 18;
  const float* src = dir ? (m ? whb : wzb) : (m ? whf : wzf);
  const float* p = src + ((size_t)(l*512 + o)*512 + i8*8);
  float4 v0 = *(const float4*)p;
  float4 v1 = *(const float4*)(p+4);
  unsigned short* q = wbf + ((((size_t)(dir*4 + l)*2 + m)*512 + o)*512 + i8*8);
  u32x4 outv;
  outv[0] = (unsigned)f2bf(v0.x) | ((unsigned)f2bf(v0.y)<<16);
  outv[1] = (unsigned)f2bf(v0.z) | ((unsigned)f2bf(v0.w)<<16);
  outv[2] = (unsigned)f2bf(v1.x) | ((unsigned)f2bf(v1.y)<<16);
  outv[3] = (unsigned)f2bf(v1.z) | ((unsigned)f2bf(v1.w)<<16);
  *(u32x4*)q = outv;
}

__global__ __launch_bounds__(256) void prep_fw(
    const float* __restrict__ fw, unsigned short* __restrict__ outw)
{
  int idx = blockIdx.x*256 + threadIdx.x;   // 65536
  const float* p = fw + (size_t)idx*8;
  float4 v0 = *(const float4*)p;
  float4 v1 = *(const float4*)(p+4);
  u32x4 outv;
  outv[0] = (unsigned)f2bf(v0.x) | ((unsigned)f2bf(v0.y)<<16);
  outv[1] = (unsigned)f2bf(v0.z) | ((unsigned)f2bf(v0.w)<<16);
  outv[2] = (unsigned)f2bf(v1.x) | ((unsigned)f2bf(v1.y)<<16);
  outv[3] = (unsigned)f2bf(v1.z) | ((unsigned)f2bf(v1.w)<<16);
  *(u32x4*)(outw + (size_t)idx*8) = outv;
}

__global__ __launch_bounds__(256) void prep_x(
    const float* __restrict__ x, unsigned short* __restrict__ X0)
{
  int idx = blockIdx.x*256 + threadIdx.x;   // 4194304
  int j8  = idx & 63;
  int s   = (idx >> 6) & 4095;
  int b   = (idx >> 18) & 7;
  int dir = idx >> 21;
  int srcs = dir ? (4095 - s) : s;
  const float* p = x + ((size_t)(b*SLEN + srcs)*512 + j8*8);
  float4 v0 = *(const float4*)p;
  float4 v1 = *(const float4*)(p+4);
  u32x4 outv;
  outv[0] = (unsigned)f2bf(v0.x) | ((unsigned)f2bf(v0.y)<<16);
  outv[1] = (unsigned)f2bf(v0.z) | ((unsigned)f2bf(v0.w)<<16);
  outv[2] = (unsigned)f2bf(v1.x) | ((unsigned)f2bf(v1.y)<<16);
  outv[3] = (unsigned)f2bf(v1.z) | ((unsigned)f2bf(v1.w)<<16);
  *(u32x4*)(X0 + ((size_t)((dir*NB + b)*SLEN + s)*512 + j8*8)) = outv;
}

// ---------------- gate GEMM + in-block chunk scan ----------------
// Block: 256 thr (4 waves). Tile: 128 rows (== one scan chunk) x 64 h-cols.
// After the GEMM epilogue, (a,b) are staged in LDS (aliasing the staging
// buffers) and a 64col x 4seg segmented scan produces per-token
// (P_t = prod a, h'_t = scan-from-zero) packed (u16 fixed, bf16) plus the
// chunk aggregates for the cross-chunk combine.

__global__ __launch_bounds__(256) void gate_gemm_scan(
    const unsigned short* __restrict__ X,    // group base [R][512] bf16
    const unsigned short* __restrict__ Wz,   // [512][512] bf16
    const unsigned short* __restrict__ Wh,
    const float* __restrict__ bzp, const float* __restrict__ bhp,  // [512]
    unsigned int* __restrict__ PH,           // [R][512] packed (P,h')
    float* __restrict__ Aagg, float* __restrict__ Bagg,
    int Mtiles, int CG)
{
  __shared__ __align__(16) unsigned char smem[32768 + 2048];
  unsigned short* As  = (unsigned short*)smem;              // [128][64] bf16
  unsigned short* Bzs = (unsigned short*)(smem + 16384);    // [64][64]
  unsigned short* Bhs = (unsigned short*)(smem + 24576);    // [64][64]
  unsigned int*   SC  = (unsigned int*)smem;                // [128][64] u32 (alias)
  float* SegP = (float*)(smem + 32768);                     // [4][64]
  float* SegH = (float*)(smem + 32768 + 1024);              // [4][64]

  int hw = blockIdx.x;
  int lg = (hw & 7)*Mtiles + (hw >> 3);     // XCD-chunked swizzle (grid = 8*Mtiles)
  int nt  = lg & 7;
  int mt  = lg >> 3;

  const int tid = threadIdx.x;
  const int lane = tid & 63;
  const int wv = tid >> 6;
  const int n0 = nt*64;
  const int slot = tid & 7;
  const int rowb = tid >> 3;

  f32x4 accz[2][4], acch[2][4];
  #pragma unroll
  for (int i=0;i<2;++i)
    #pragma unroll
    for (int j=0;j<4;++j){ accz[i][j] = (f32x4)(0.f); acch[i][j] = (f32x4)(0.f); }

  for (int ks=0; ks<8; ++ks){
    int k0 = ks*64;
    #pragma unroll
    for (int it=0; it<4; ++it){
      int row = rowb + it*32;
      u32x4 v = *(const u32x4*)(X + (size_t)(mt*128+row)*512 + k0 + slot*8);
      *(u32x4*)(As + row*64 + ((slot ^ (row&7))<<3)) = v;
    }
    #pragma unroll
    for (int it=0; it<2; ++it){
      int row = rowb + it*32;
      u32x4 vz = *(const u32x4*)(Wz + (size_t)(n0+row)*512 + k0 + slot*8);
      *(u32x4*)(Bzs + row*64 + ((slot ^ (row&7))<<3)) = vz;
      u32x4 vh = *(const u32x4*)(Wh + (size_t)(n0+row)*512 + k0 + slot*8);
      *(u32x4*)(Bhs + row*64 + ((slot ^ (row&7))<<3)) = vh;
    }
    __syncthreads();
    #pragma unroll
    for (int kk=0; kk<2; ++kk){
      int kslot = kk*4 + (lane >> 4);
      u32x4 af[2];
      #pragma unroll
      for (int mf=0; mf<2; ++mf){
        int row = wv*32 + mf*16 + (lane & 15);
        af[mf] = *(const u32x4*)(As + row*64 + ((kslot ^ (row&7))<<3));
      }
      #pragma unroll
      for (int nf=0; nf<4; ++nf){
        int row = nf*16 + (lane & 15);
        u32x4 bz = *(const u32x4*)(Bzs + row*64 + ((kslot ^ (row&7))<<3));
        u32x4 bh = *(const u32x4*)(Bhs + row*64 + ((kslot ^ (row&7))<<3));
        #pragma unroll
        for (int mf=0; mf<2; ++mf){
          mfma_bf16(accz[mf][nf], af[mf], bz);
          mfma_bf16(acch[mf][nf], af[mf], bh);
        }
      }
    }
    __syncthreads();
  }
  mfma_fence();

  // ---- epilogue: gates -> packed fixed-point (a,b) into LDS ----
  #pragma unroll
  for (int nf=0; nf<4; ++nf){
    int colL = nf*16 + (lane & 15);
    float bz = bzp[n0 + colL];
    float bh = bhp[n0 + colL];
    #pragma unroll
    for (int mf=0; mf<2; ++mf){
      int rloc = wv*32 + mf*16 + ((lane>>4)<<2);
      #pragma unroll
      for (int r=0; r<4; ++r){
        float zp = accz[mf][nf][r] + bz;
        float hp = acch[mf][nf][r] + bh;
        float sg = 1.f/(1.f + __expf(-zp));
        float th = 1.f - 2.f/(1.f + __expf(2.f*hp));
        float a = 1.f - sg;
        a = fminf(fmaxf(a, 1e-8f), 1.0f);   // ref clip hi = 1-1e-8, rounds to 1.0f
        float bv = sg*th;                    // |bv| < 1
        unsigned aq = (unsigned)fmaf(a, 65535.f, 0.5f);
        unsigned bq = (unsigned)fmaf(bv, 32767.5f, 32768.0f);
        SC[(rloc + r)*64 + colL] = aq | (bq << 16);
      }
    }
  }
  __syncthreads();

  // ---- pass 1: per-segment local scan (in-place LDS rewrite) ----
  const int col = tid & 63;
  const int seg = tid >> 6;       // == wave id, uniform per wave
  float P = 1.f, Hl = 0.f;
  #pragma unroll
  for (int r=0; r<32; ++r){
    int row = seg*32 + r;
    float a, b; decode_ab(SC[row*64 + col], a, b);
    Hl = fmaf(a, Hl, b);
    P *= a;
    unsigned pq = (unsigned)fmaf(P, 65535.f, 0.5f);
    SC[row*64 + col] = pq | ((unsigned)f2bf(Hl) << 16);
  }
  SegP[seg*64 + col] = P;
  SegH[seg*64 + col] = Hl;
  __syncthreads();

  // ---- segment prefixes (<=3 serial combines, wave-uniform trip count) ----
  float Ppre = 1.f, Hpre = 0.f;
  for (int j=0; j<seg; ++j){
    Hpre = fmaf(SegP[j*64 + col], Hpre, SegH[j*64 + col]);
    Ppre *= SegP[j*64 + col];
  }

  // ---- pass 2: apply prefix, write per-token (P,h') + chunk aggregates ----
  const int rowbase = mt*128;
  float Pg = 1.f, Hg = 0.f;
  #pragma unroll
  for (int r=0; r<32; ++r){
    int row = seg*32 + r;
    unsigned v = SC[row*64 + col];
    float Pl = (float)(v & 0xffffu) * (1.f/65535.f);
    float Hlv = bf2f((unsigned short)(v >> 16));
    Pg = Ppre * Pl;
    Hg = fmaf(Pl, Hpre, Hlv);
    unsigned pq = (unsigned)fmaf(Pg, 65535.f, 0.5f);
    PH[(size_t)(rowbase + row)*512 + n0 + col] = pq | ((unsigned)f2bf(Hg) << 16);
  }
  if (seg == 3){
    int chain = (mt >> 5)*512 + n0 + col;   // batch-in-group * 512 + h
    int c = mt & 31;                        // chunk within sequence
    Aagg[c*CG + chain] = Pg;
    Bagg[c*CG + chain] = Hg;
  }
}

// ---------------- cross-chunk combine (tiny) ----------------

__global__ __launch_bounds__(256) void scan_p2(
    const float* __restrict__ Aagg, const float* __restrict__ Bagg,
    float* __restrict__ Hin, int CG)
{
  int chain = blockIdx.x*256 + threadIdx.x;  // CG threads
  float hv = 0.f;
  #pragma unroll
  for (int c=0; c<NCHUNK; ++c){
    Hin[c*CG + chain] = hv;
    hv = fmaf(Aagg[c*CG + chain], hv, Bagg[c*CG + chain]);
  }
}

// ---------------- h reconstruction + residual + LayerNorm (in-place X) ----------------

__global__ __launch_bounds__(256) void recon_ln(
    const unsigned int* __restrict__ PH,     // group [R][512]
    const float* __restrict__ Hin,           // [32][CG]
    unsigned short* __restrict__ Xio,        // group [R][512] bf16 in/out
    const float* __restrict__ g, const float* __restrict__ bta,
    int resid, int CG)
{
  int token = blockIdx.x*4 + (threadIdx.x >> 6);
  int lane = threadIdx.x & 63;
  size_t base = (size_t)token*512 + lane*8;
  u32x4 p0 = *(const u32x4*)(PH + base);
  u32x4 p1 = *(const u32x4*)(PH + base + 4);
  int c  = (token >> 7) & 31;
  int bl = token >> 12;
  const float* hin = Hin + (size_t)c*CG + bl*512 + lane*8;
  f32x4 h0 = *(const f32x4*)hin;
  f32x4 h1 = *(const f32x4*)(hin + 4);
  float v[8];
  #pragma unroll
  for (int j=0; j<4; ++j){
    v[j]   = fmaf((float)(p0[j] & 0xffffu)*(1.f/65535.f), h0[j], bf2f((unsigned short)(p0[j] >> 16)));
    v[4+j] = fmaf((float)(p1[j] & 0xffffu)*(1.f/65535.f), h1[j], bf2f((unsigned short)(p1[j] >> 16)));
  }
  if (resid){
    u32x4 xv = *(const u32x4*)(Xio + base);
    #pragma unroll
    for (int w=0; w<4; ++w){
      v[2*w]   += bf2f((unsigned short)(xv[w] & 0xffffu));
      v[2*w+1] += bf2f((unsigned short)(xv[w] >> 16));
    }
  }
  float s = 0.f, s2 = 0.f;
  #pragma unroll
  for (int j=0; j<8; ++j){ s += v[j]; s2 += v[j]*v[j]; }
  #pragma unroll
  for (int o=1; o<64; o<<=1){ s += __shfl_xor(s, o, 64); s2 += __shfl_xor(s2, o, 64); }
  float mu = s * (1.f/512.f);
  float var = s2 * (1.f/512.f) - mu*mu;
  float inv = rsqrtf(var + 1e-5f);
  float4 g0 = *(const float4*)(g + lane*8);
  float4 g1 = *(const float4*)(g + lane*8 + 4);
  float4 b0 = *(const float4*)(bta + lane*8);
  float4 b1 = *(const float4*)(bta + lane*8 + 4);
  float gg[8]  = {g0.x,g0.y,g0.z,g0.w,g1.x,g1.y,g1.z,g1.w};
  float bbv[8] = {b0.x,b0.y,b0.z,b0.w,b1.x,b1.y,b1.z,b1.w};
  u32x4 outv;
  #pragma unroll
  for (int w=0; w<4; ++w){
    float y0 = (v[2*w]   - mu)*inv*gg[2*w]   + bbv[2*w];
    float y1 = (v[2*w+1] - mu)*inv*gg[2*w+1] + bbv[2*w+1];
    outv[w] = (unsigned)f2bf(y0) | ((unsigned)f2bf(y1) << 16);
  }
  *(u32x4*)(Xio + base) = outv;
}

// ---------------- fusion GEMM: out = [fwd, flip(bwd)] @ Wf^T + fb ----------------

__global__ __launch_bounds__(256) void fusion_gemm(
    const unsigned short* __restrict__ Xf,   // [2*BSROWS][512] final LN outputs
    const unsigned short* __restrict__ Wf,   // [512][1024] bf16
    const float* __restrict__ fb,
    float* __restrict__ outp)
{
  __shared__ __align__(16) unsigned short As[128*64];
  __shared__ __align__(16) unsigned short Bs[64*64];

  int hw = blockIdx.x;
  int lg = (hw & 7)*256 + (hw >> 3);   // 2048 blocks
  int nt = lg & 7;
  int mt = lg >> 3;                    // 0..255

  const int tid = threadIdx.x;
  const int lane = tid & 63;
  const int wv = tid >> 6;
  const int n0 = nt*64;
  const int slot = tid & 7;
  const int rowb = tid >> 3;

  f32x4 acc[2][4];
  #pragma unroll
  for (int i=0;i<2;++i)
    #pragma unroll
    for (int j=0;j<4;++j) acc[i][j] = (f32x4)(0.f);

  for (int ks=0; ks<16; ++ks){
    int k0 = ks*64;
    const unsigned short* Abase = Xf + ((k0 >= 512) ? (size_t)BSROWS*512 : 0);
    int kc = k0 & 511;
    #pragma unroll
    for (int it=0; it<4; ++it){
      int row = rowb + it*32;
      int rg = mt*128 + row;
      int sr = (k0 >= 512) ? (rg ^ 4095) : rg;   // flip s within batch for bwd half
      u32x4 v = *(const u32x4*)(Abase + (size_t)sr*512 + kc + slot*8);
      *(u32x4*)(As + row*64 + ((slot ^ (row&7))<<3)) = v;
    }
    #pragma unroll
    for (int it=0; it<2; ++it){
      int row = rowb + it*32;
      u32x4 v = *(const u32x4*)(Wf + (size_t)(n0+row)*1024 + k0 + slot*8);
      *(u32x4*)(Bs + row*64 + ((slot ^ (row&7))<<3)) = v;
    }
    __syncthreads();
    #pragma unroll
    for (int kk=0; kk<2; ++kk){
      int kslot = kk*4 + (lane >> 4);
      u32x4 af[2];
      #pragma unroll
      for (int mf=0; mf<2; ++mf){
        int row = wv*32 + mf*16 + (lane & 15);
        af[mf] = *(const u32x4*)(As + row*64 + ((kslot ^ (row&7))<<3));
      }
      #pragma unroll
      for (int nf=0; nf<4; ++nf){
        int row = nf*16 + (lane & 15);
        u32x4 bv = *(const u32x4*)(Bs + row*64 + ((kslot ^ (row&7))<<3));
        #pragma unroll
        for (int mf=0; mf<2; ++mf) mfma_bf16(acc[mf][nf], af[mf], bv);
      }
    }
    __syncthreads();
  }
  mfma_fence();

  #pragma unroll
  for (int nf=0; nf<4; ++nf){
    int col = n0 + nf*16 + (lane & 15);
    float bias = fb[col];
    #pragma unroll
    for (int mf=0; mf<2; ++mf){
      int rb = mt*128 + wv*32 + mf*16 + ((lane>>4)<<2);
      #pragma unroll
      for (int r=0; r<4; ++r)
        outp[(size_t)(rb + r)*512 + col] = acc[mf][nf][r] + bias;
    }
  }
}

// ---------------- launch ----------------

extern "C" void kernel_launch(void* const* d_in, const int* in_sizes, int n_in,
                              void* d_out, int out_size, void* d_ws, size_t ws_size,
                              hipStream_t stream)
{
  (void)in_sizes; (void)n_in; (void)out_size;
  const float* x   = (const float*)d_in[0];
  const float* wzf = (const float*)d_in[1];
  const float* bzf = (const float*)d_in[2];
  const float* whf = (const float*)d_in[3];
  const float* bhf = (const float*)d_in[4];
  const float* wzb = (const float*)d_in[5];
  const float* bzb = (const float*)d_in[6];
  const float* whb = (const float*)d_in[7];
  const float* bhb = (const float*)d_in[8];
  const float* fw  = (const float*)d_in[9];
  const float* fbb = (const float*)d_in[10];
  const float* lng = (const float*)d_in[11];
  const float* lnb = (const float*)d_in[12];
  float* outp = (float*)d_out;

  // Pick the largest per-direction batch-group count SG that fits ws_size.
  const size_t WbfB = (size_t)16*512*512*2;        // 8 MiB
  const size_t WfbB = (size_t)512*1024*2;          // 1 MiB
  const size_t XB   = (size_t)2*BSROWS*512*2;      // 64 MiB
  const size_t aggB = (size_t)4096*NCHUNK*4;       // 512 KiB (max CG)
  int SG = 8;
  for (int c = 1; c <= 8; c <<= 1){
    size_t need = WbfB + WfbB + XB + 3*aggB
                + ((size_t)BSROWS/c)*512*4          // PH
                + 1024;
    if (need <= ws_size){ SG = c; break; }
  }
  const int R  = BSROWS / SG;      // rows per group
  const int NBg = NB / SG;         // batches per group
  const int CG = NBg * 512;        // scan chains per group
  const int Mtiles = R / 128;

  char* ws = (char*)d_ws;
  size_t o = 0;
  unsigned short* Wbf = (unsigned short*)(ws + o); o += WbfB;
  unsigned short* Wfb = (unsigned short*)(ws + o); o += WfbB;
  unsigned short* X   = (unsigned short*)(ws + o); o += XB;
  unsigned int*   PH  = (unsigned int*)  (ws + o); o += (size_t)R*512*4;
  float* Aagg = (float*)(ws + o); o += aggB;
  float* Bagg = (float*)(ws + o); o += aggB;
  float* Hin  = (float*)(ws + o); o += aggB;

  prep_w <<<2048, 256, 0, stream>>>(wzf, whf, wzb, whb, Wbf);
  prep_fw<<<256,  256, 0, stream>>>(fw, Wfb);
  prep_x <<<16384,256, 0, stream>>>(x, X);

  for (int dir = 0; dir < 2; ++dir){
    const float* bz = dir ? bzb : bzf;
    const float* bh = dir ? bhb : bhf;
    for (int g = 0; g < SG; ++g){
      unsigned short* Xg = X + ((size_t)dir*BSROWS + (size_t)g*R)*512;
      for (int l = 0; l < NLAYER; ++l){
        const unsigned short* Wz = Wbf + ((size_t)((dir*4 + l)*2 + 0))*(512*512);
        const unsigned short* Wh = Wbf + ((size_t)((dir*4 + l)*2 + 1))*(512*512);
        gate_gemm_scan<<<Mtiles*8, 256, 0, stream>>>(Xg, Wz, Wh, bz + l*512, bh + l*512,
                                                     PH, Aagg, Bagg, Mtiles, CG);
        scan_p2 <<<CG/256, 256, 0, stream>>>(Aagg, Bagg, Hin, CG);
        recon_ln<<<R/4,    256, 0, stream>>>(PH, Hin, Xg, lng, lnb, l > 0 ? 1 : 0, CG);
      }
    }
  }
  fusion_gemm<<<2048, 256, 0, stream>>>(X, Wfb, fbb, outp);
}